// Round 2
// baseline (1354.476 us; speedup 1.0000x reference)
//
#include <hip/hip_runtime.h>
#include <hip/hip_bf16.h>
#include <math.h>

typedef __hip_bfloat16 bf16;
typedef __attribute__((ext_vector_type(8))) short bf16x8;
typedef __attribute__((ext_vector_type(4))) float f32x4;

static constexpr int DD = 1024;    // D
static constexpr int BB = 4;       // batch
static constexpr int SS = 4096;    // seq
static constexpr int FD = 4096;    // 4D
static constexpr int GDIM = 2048;  // 2D
static constexpr long SD = (long)SS * DD;  // per-batch x elements

// ---------------- async global->LDS (16B per lane) ----------------
__device__ __forceinline__ void gl2lds16(const bf16* g, bf16* l) {
    __builtin_amdgcn_global_load_lds(
        (const __attribute__((address_space(1))) void*)g,
        (__attribute__((address_space(3))) void*)l, 16, 0, 0);
}

// ---------------- GEMM: C[M,N] = A[M,K] * BT[N,K]^T, all bf16 in ----------------
// EPI 0: +bias[row], store bf16     (GEMM1: omega_T; bias indexed by output row)
// EPI 1: +bias[col], gelu, bf16     (GEMM2)
// EPI 2: +bias[col]+X[row,col], f32 (GEMM3 + residual)
template <int EPI>
__global__ __launch_bounds__(256) void gemm_bt(
    const bf16* __restrict__ A, const bf16* __restrict__ BT, void* __restrict__ Cp,
    const float* __restrict__ bias, const float* __restrict__ Xadd,
    int M, int N, int K)
{
    __shared__ __align__(16) bf16 As[128 * 32];
    __shared__ __align__(16) bf16 Bs[128 * 32];
    const int t = threadIdx.x;
    const int l = t & 63, wv = t >> 6;
    const long m0 = (long)blockIdx.y * 128, n0 = (long)blockIdx.x * 128;

    // staging: each wave stages 16 rows per call, 2 calls per matrix (rows +0 / +64)
    const int rowOff = wv * 16 + (l >> 2);               // 0..63
    const int kgrp = (l & 3) ^ ((l >> 2) & 3);           // XOR swizzle on k-chunk
    const bf16* pa = A + (m0 + rowOff) * (long)K + kgrp * 8;
    const bf16* pa2 = pa + 64L * K;
    const bf16* pb = BT + (n0 + rowOff) * (long)K + kgrp * 8;
    const bf16* pb2 = pb + 64L * K;
    bf16* la = &As[(wv * 16) * 32];
    bf16* la2 = &As[(wv * 16 + 64) * 32];
    bf16* lb = &Bs[(wv * 16) * 32];
    bf16* lb2 = &Bs[(wv * 16 + 64) * 32];

    f32x4 acc[4][4];
#pragma unroll
    for (int i = 0; i < 4; i++)
#pragma unroll
        for (int j = 0; j < 4; j++) acc[i][j] = (f32x4){0.f, 0.f, 0.f, 0.f};

    const int wr = wv >> 1, wc = wv & 1;
    const int fm = l & 15, q = l >> 4;
    const int sw = (q ^ (fm & 3)) << 3;  // swizzled chunk offset (elements)

    for (int k0 = 0; k0 < K; k0 += 32) {
        gl2lds16(pa, la);
        gl2lds16(pa2, la2);
        gl2lds16(pb, lb);
        gl2lds16(pb2, lb2);
        pa += 32; pa2 += 32; pb += 32; pb2 += 32;
        __syncthreads();
        bf16x8 af[4], bfr[4];
#pragma unroll
        for (int i = 0; i < 4; i++)
            af[i] = *(const bf16x8*)&As[(wr * 64 + i * 16 + fm) * 32 + sw];
#pragma unroll
        for (int j = 0; j < 4; j++)
            bfr[j] = *(const bf16x8*)&Bs[(wc * 64 + j * 16 + fm) * 32 + sw];
#pragma unroll
        for (int i = 0; i < 4; i++)
#pragma unroll
            for (int j = 0; j < 4; j++)
                acc[i][j] = __builtin_amdgcn_mfma_f32_16x16x32_bf16(af[i], bfr[j], acc[i][j], 0, 0, 0);
        __syncthreads();
    }

#pragma unroll
    for (int i = 0; i < 4; i++) {
#pragma unroll
        for (int j = 0; j < 4; j++) {
            const long col = n0 + wc * 64 + j * 16 + fm;
            const long rB = m0 + wr * 64 + i * 16 + q * 4;
#pragma unroll
            for (int r = 0; r < 4; r++) {
                const long row = rB + r;
                float v = acc[i][j][r];
                if (EPI == 0) {
                    v += bias[row];
                    ((bf16*)Cp)[row * (long)N + col] = __float2bfloat16(v);
                } else if (EPI == 1) {
                    v += bias[col];
                    v = 0.5f * v * (1.0f + erff(v * 0.70710678118654752f));
                    ((bf16*)Cp)[row * (long)N + col] = __float2bfloat16(v);
                } else {
                    v += bias[col] + Xadd[row * (long)N + col];
                    ((float*)Cp)[row * (long)N + col] = v;
                }
            }
        }
    }
}

// ---------------- fp32 -> bf16 straight convert ----------------
__global__ void conv_bf16(const float* __restrict__ in, bf16* __restrict__ out, long n) {
    long i = ((long)blockIdx.x * 256 + threadIdx.x) * 4;
    if (i >= n) return;
    const float4 v = *(const float4*)(in + i);
    bf16 o[4] = {__float2bfloat16(v.x), __float2bfloat16(v.y),
                 __float2bfloat16(v.z), __float2bfloat16(v.w)};
    *(uint2*)(out + i) = *(uint2*)o;
}

// ---------------- fp32 (R x C) -> bf16 (C x R) transpose ----------------
__global__ void transpose_f32_bf16(const float* __restrict__ in, bf16* __restrict__ out,
                                   int R, int C) {
    __shared__ float tl[64][65];
    const int r0 = blockIdx.y * 64, c0 = blockIdx.x * 64;
    const int tr = threadIdx.x >> 6, tc = threadIdx.x & 63;
#pragma unroll
    for (int k = 0; k < 16; k++) {
        int r = k * 4 + tr;
        tl[r][tc] = in[(long)(r0 + r) * C + c0 + tc];
    }
    __syncthreads();
#pragma unroll
    for (int k = 0; k < 16; k++) {
        int r = k * 4 + tr;
        out[(long)(c0 + r) * R + r0 + tc] = __float2bfloat16(tl[tc][r]);
    }
}

// ---------------- serial part: phase cumsum + complex memory, one wave per d ----------------
// omegaT, xT: (D, S) bf16 for this batch.  ctx: (4D, S) bf16 for this batch.
__global__ __launch_bounds__(256) void scan_kernel(
    const bf16* __restrict__ omegaT, const bf16* __restrict__ xT,
    const float* __restrict__ log_scale, bf16* __restrict__ ctx)
{
    const int d = blockIdx.x * 4 + (threadIdx.x >> 6);
    const int lane = threadIdx.x & 63;
    const float sc = expf(log_scale[d]);
    const bf16* po = omegaT + (long)d * SS;
    const bf16* px = xT + (long)d * SS;
    bf16* pc = ctx + (long)d * SS;

    float phi_c = 0.f, mr_c = 0.f, mi_c = 0.f;
    for (int tchunk = 0; tchunk < SS / 64; tchunk++) {
        const int s = tchunk * 64 + lane;
        const float pos = (float)(s + 1);
        float w = __bfloat162float(po[s]) * sc * rsqrtf(pos);
        // inclusive wave scan of w
#pragma unroll
        for (int dlt = 1; dlt < 64; dlt <<= 1) {
            float v = __shfl_up(w, dlt, 64);
            if (lane >= dlt) w += v;
        }
        const float phi = phi_c + w;
        float sph, cph;
        sincosf(phi, &sph, &cph);
        const float xv = __bfloat162float(px[s]);
        const float cr = xv * cph, ci = xv * sph;
        float crs = cr, cis = ci;
#pragma unroll
        for (int dlt = 1; dlt < 64; dlt <<= 1) {
            float v1 = __shfl_up(crs, dlt, 64);
            float v2 = __shfl_up(cis, dlt, 64);
            if (lane >= dlt) { crs += v1; cis += v2; }
        }
        const float invp = 1.0f / pos;
        const float mr = (mr_c + crs) * invp;
        const float mi = (mi_c + cis) * invp;
        const float rr = mr * cph + mi * sph;
        const float ri = mi * cph - mr * sph;
        pc[s] = __float2bfloat16(cr);
        pc[(long)DD * SS + s] = __float2bfloat16(ci);
        pc[2L * DD * SS + s] = __float2bfloat16(rr);
        pc[3L * DD * SS + s] = __float2bfloat16(ri);
        phi_c += __shfl(w, 63, 64);
        mr_c += __shfl(crs, 63, 64);
        mi_c += __shfl(cis, 63, 64);
    }
}

// ---------------- per-s LN stats over f (split-f + atomics), per batch ----------------
__global__ void zero_f32(float* p, int n) {
    int i = blockIdx.x * 256 + threadIdx.x;
    if (i < n) p[i] = 0.f;
}

__global__ void stats_kernel(const bf16* __restrict__ ctx, float* __restrict__ sums,
                             float* __restrict__ sqs) {
    const int s = blockIdx.x * 256 + threadIdx.x;  // 0..S-1
    const int f0 = blockIdx.y * 512;
    const bf16* p = ctx + (long)f0 * SS + s;
    float sm = 0.f, sq = 0.f;
    for (int f = 0; f < 512; f++) {
        float v = __bfloat162float(p[(long)f * SS]);
        sm += v;
        sq += v * v;
    }
    atomicAdd(&sums[s], sm);
    atomicAdd(&sqs[s], sq);
}

// ---------------- LayerNorm + transpose back to s-major bf16 (per batch) ----------------
__global__ void lnt_kernel(const bf16* __restrict__ ctx, const float* __restrict__ sums,
                           const float* __restrict__ sqs, const float* __restrict__ gamma,
                           const float* __restrict__ beta, bf16* __restrict__ hln) {
    __shared__ float tl[64][65];
    const int f0 = blockIdx.y * 64, s0 = blockIdx.x * 64;
    const int tr = threadIdx.x >> 6, tc = threadIdx.x & 63;
    const bf16* ip = ctx + (long)f0 * SS + s0;
#pragma unroll
    for (int k = 0; k < 16; k++) {
        int fi = k * 4 + tr;
        tl[fi][tc] = __bfloat162float(ip[(long)fi * SS + tc]);
    }
    __syncthreads();
#pragma unroll
    for (int k = 0; k < 16; k++) {
        const int si = k * 4 + tr;
        const int s = s0 + si;
        const float mu = sums[s] * (1.0f / FD);
        const float var = sqs[s] * (1.0f / FD) - mu * mu;
        const float is = rsqrtf(var + 1e-5f);
        const int f = f0 + tc;
        const float v = (tl[tc][si] - mu) * is * gamma[f] + beta[f];
        hln[(long)s * FD + f] = __float2bfloat16(v);
    }
}

// ---------------- launch ----------------
extern "C" void kernel_launch(void* const* d_in, const int* in_sizes, int n_in,
                              void* d_out, int out_size, void* d_ws, size_t ws_size,
                              hipStream_t stream)
{
    const float* x = (const float*)d_in[0];
    const float* Wo = (const float*)d_in[1];
    const float* bo = (const float*)d_in[2];
    const float* lsc = (const float*)d_in[3];
    const float* gam = (const float*)d_in[4];
    const float* bet = (const float*)d_in[5];
    const float* W1 = (const float*)d_in[6];
    const float* b1 = (const float*)d_in[7];
    const float* W2 = (const float*)d_in[8];
    const float* b2 = (const float*)d_in[9];

    char* ws = (char*)d_ws;
    const size_t MB = 1024 * 1024;
    // Persistent across batches:
    bf16* W1T = (bf16*)(ws + 0);           // 16 MB  (2048 x 4096)
    bf16* W2T = (bf16*)(ws + 16 * MB);     //  4 MB  (1024 x 2048)
    bf16* WoT = (bf16*)(ws + 20 * MB);     //  2 MB  (1024 x 1024)
    float* sums = (float*)(ws + 22 * MB);  // 16 KB
    float* sqs = sums + SS;                // 16 KB
    // Per-batch (reused each b), lifetime-aliased:
    bf16* hln = (bf16*)(ws + 23 * MB);     // 32 MB  [23,55)  h_ln (s,4D), written after scan
    bf16* xb  = (bf16*)(ws + 23 * MB);     //  8 MB  [23,31)  x_b bf16 (s,d), dead after GEMM1
    bf16* omT = (bf16*)(ws + 31 * MB);     //  8 MB  [31,39)  omega^T (d,s), dead after scan
    bf16* xT  = (bf16*)(ws + 39 * MB);     //  8 MB  [39,47)  x^T (d,s), dead after scan
    bf16* ctx = (bf16*)(ws + 55 * MB);     // 32 MB  [55,87)  ctx^T (4D,s), dead after lnt
    bf16* h1  = (bf16*)(ws + 55 * MB);     // 16 MB  [55,71)  aliases ctx
    // Peak workspace: 87 MB.

    // Weight conversions (once per call; ws is re-poisoned before every call)
    transpose_f32_bf16<<<dim3(DD / 64, DD / 64), 256, 0, stream>>>(Wo, WoT, DD, DD);
    transpose_f32_bf16<<<dim3(GDIM / 64, FD / 64), 256, 0, stream>>>(W1, W1T, FD, GDIM);
    transpose_f32_bf16<<<dim3(DD / 64, GDIM / 64), 256, 0, stream>>>(W2, W2T, GDIM, DD);

    for (int b = 0; b < BB; b++) {
        const float* xb_f32 = x + (long)b * SD;
        // x slice -> bf16 (s,d) and bf16 (d,s)
        conv_bf16<<<(int)(SD / 1024), 256, 0, stream>>>(xb_f32, xb, SD);
        transpose_f32_bf16<<<dim3(DD / 64, SS / 64), 256, 0, stream>>>(xb_f32, xT, SS, DD);

        // GEMM1: omega^T = Wo^T (1024x1024) * x^T  (A=WoT, BT=xb rows are s with K=d)
        gemm_bt<0><<<dim3(SS / 128, DD / 128), 256, 0, stream>>>(
            WoT, xb, omT, bo, nullptr, DD, SS, DD);

        // phase scan + complex memory -> ctx (4D, S)
        scan_kernel<<<DD / 4, 256, 0, stream>>>(omT, xT, lsc, ctx);

        // LN stats over f
        zero_f32<<<(2 * SS + 255) / 256, 256, 0, stream>>>(sums, 2 * SS);
        stats_kernel<<<dim3(SS / 256, FD / 512), 256, 0, stream>>>(ctx, sums, sqs);

        // LN + transpose to s-major bf16
        lnt_kernel<<<dim3(SS / 64, FD / 64), 256, 0, stream>>>(ctx, sums, sqs, gam, bet, hln);

        // GEMM2: h1 = gelu(hln * W1 + b1)   (BT = W1T: 2048x4096)
        gemm_bt<1><<<dim3(GDIM / 128, SS / 128), 256, 0, stream>>>(
            hln, W1T, h1, b1, nullptr, SS, GDIM, FD);

        // GEMM3: out_b = x_b + h1 * W2 + b2 (BT = W2T: 1024x2048), fp32 out
        gemm_bt<2><<<dim3(DD / 128, SS / 128), 256, 0, stream>>>(
            h1, W2T, (float*)d_out + (long)b * SD, b2, xb_f32, SS, DD, GDIM);
    }
}

// Round 3
// 1216.662 us; speedup vs baseline: 1.1133x; 1.1133x over previous
//
#include <hip/hip_runtime.h>
#include <hip/hip_bf16.h>
#include <math.h>

typedef __hip_bfloat16 bf16;
typedef __attribute__((ext_vector_type(8))) short bf16x8;
typedef __attribute__((ext_vector_type(4))) float f32x4;

static constexpr int DD = 1024;    // D
static constexpr int BB = 4;       // batch
static constexpr int SS = 4096;    // seq
static constexpr int FD = 4096;    // 4D
static constexpr int GDIM = 2048;  // 2D
static constexpr long SD = (long)SS * DD;  // per-batch x elements

// ---------------- async global->LDS (16B per lane) ----------------
__device__ __forceinline__ void gl2lds16(const bf16* g, bf16* l) {
    __builtin_amdgcn_global_load_lds(
        (const __attribute__((address_space(1))) void*)g,
        (__attribute__((address_space(3))) void*)l, 16, 0, 0);
}

// ---------------- GEMM: C[M,N] = A[M,K] * BT[N,K]^T, all bf16 in ----------------
// EPI 0: +bias[row], store bf16     (GEMM1: omega_T; bias indexed by output row)
// EPI 1: +bias[col], gelu, bf16     (GEMM2)
// EPI 2: +bias[col]+X[row,col], f32 (GEMM3 + residual)
template <int EPI>
__global__ __launch_bounds__(256) void gemm_bt(
    const bf16* __restrict__ A, const bf16* __restrict__ BT, void* __restrict__ Cp,
    const float* __restrict__ bias, const float* __restrict__ Xadd,
    int M, int N, int K)
{
    __shared__ __align__(16) bf16 As[128 * 32];
    __shared__ __align__(16) bf16 Bs[128 * 32];
    const int t = threadIdx.x;
    const int l = t & 63, wv = t >> 6;
    const long m0 = (long)blockIdx.y * 128, n0 = (long)blockIdx.x * 128;

    // staging: each wave stages 16 rows per call, 2 calls per matrix (rows +0 / +64)
    const int rowOff = wv * 16 + (l >> 2);               // 0..63
    const int kgrp = (l & 3) ^ ((l >> 2) & 3);           // XOR swizzle on k-chunk
    const bf16* pa = A + (m0 + rowOff) * (long)K + kgrp * 8;
    const bf16* pa2 = pa + 64L * K;
    const bf16* pb = BT + (n0 + rowOff) * (long)K + kgrp * 8;
    const bf16* pb2 = pb + 64L * K;
    bf16* la = &As[(wv * 16) * 32];
    bf16* la2 = &As[(wv * 16 + 64) * 32];
    bf16* lb = &Bs[(wv * 16) * 32];
    bf16* lb2 = &Bs[(wv * 16 + 64) * 32];

    f32x4 acc[4][4];
#pragma unroll
    for (int i = 0; i < 4; i++)
#pragma unroll
        for (int j = 0; j < 4; j++) acc[i][j] = (f32x4){0.f, 0.f, 0.f, 0.f};

    const int wr = wv >> 1, wc = wv & 1;
    const int fm = l & 15, q = l >> 4;
    const int sw = (q ^ (fm & 3)) << 3;  // swizzled chunk offset (elements)

    for (int k0 = 0; k0 < K; k0 += 32) {
        gl2lds16(pa, la);
        gl2lds16(pa2, la2);
        gl2lds16(pb, lb);
        gl2lds16(pb2, lb2);
        pa += 32; pa2 += 32; pb += 32; pb2 += 32;
        __syncthreads();
        bf16x8 af[4], bfr[4];
#pragma unroll
        for (int i = 0; i < 4; i++)
            af[i] = *(const bf16x8*)&As[(wr * 64 + i * 16 + fm) * 32 + sw];
#pragma unroll
        for (int j = 0; j < 4; j++)
            bfr[j] = *(const bf16x8*)&Bs[(wc * 64 + j * 16 + fm) * 32 + sw];
#pragma unroll
        for (int i = 0; i < 4; i++)
#pragma unroll
            for (int j = 0; j < 4; j++)
                acc[i][j] = __builtin_amdgcn_mfma_f32_16x16x32_bf16(af[i], bfr[j], acc[i][j], 0, 0, 0);
        __syncthreads();
    }

#pragma unroll
    for (int i = 0; i < 4; i++) {
#pragma unroll
        for (int j = 0; j < 4; j++) {
            const long col = n0 + wc * 64 + j * 16 + fm;
            const long rB = m0 + wr * 64 + i * 16 + q * 4;
#pragma unroll
            for (int r = 0; r < 4; r++) {
                const long row = rB + r;
                float v = acc[i][j][r];
                if (EPI == 0) {
                    v += bias[row];
                    ((bf16*)Cp)[row * (long)N + col] = __float2bfloat16(v);
                } else if (EPI == 1) {
                    v += bias[col];
                    v = 0.5f * v * (1.0f + erff(v * 0.70710678118654752f));
                    ((bf16*)Cp)[row * (long)N + col] = __float2bfloat16(v);
                } else {
                    v += bias[col] + Xadd[row * (long)N + col];
                    ((float*)Cp)[row * (long)N + col] = v;
                }
            }
        }
    }
}

// ---------------- fp32 -> bf16 straight convert ----------------
__global__ void conv_bf16(const float* __restrict__ in, bf16* __restrict__ out, long n) {
    long i = ((long)blockIdx.x * 256 + threadIdx.x) * 4;
    if (i >= n) return;
    const float4 v = *(const float4*)(in + i);
    bf16 o[4] = {__float2bfloat16(v.x), __float2bfloat16(v.y),
                 __float2bfloat16(v.z), __float2bfloat16(v.w)};
    *(uint2*)(out + i) = *(uint2*)o;
}

// ---------------- fp32 (R x C) -> bf16 (C x R) transpose ----------------
__global__ void transpose_f32_bf16(const float* __restrict__ in, bf16* __restrict__ out,
                                   int R, int C) {
    __shared__ float tl[64][65];
    const int r0 = blockIdx.y * 64, c0 = blockIdx.x * 64;
    const int tr = threadIdx.x >> 6, tc = threadIdx.x & 63;
#pragma unroll
    for (int k = 0; k < 16; k++) {
        int r = k * 4 + tr;
        tl[r][tc] = in[(long)(r0 + r) * C + c0 + tc];
    }
    __syncthreads();
#pragma unroll
    for (int k = 0; k < 16; k++) {
        int r = k * 4 + tr;
        out[(long)(c0 + r) * R + r0 + tc] = __float2bfloat16(tl[tc][r]);
    }
}

// ---------------- serial part: phase cumsum + complex memory, one wave per d ----------------
// omegaT, xT: (D, S) bf16 for this batch.  ctx: (4D, S) bf16 for this batch.
__global__ __launch_bounds__(256) void scan_kernel(
    const bf16* __restrict__ omegaT, const bf16* __restrict__ xT,
    const float* __restrict__ log_scale, bf16* __restrict__ ctx)
{
    const int d = blockIdx.x * 4 + (threadIdx.x >> 6);
    const int lane = threadIdx.x & 63;
    const float sc = expf(log_scale[d]);
    const bf16* po = omegaT + (long)d * SS;
    const bf16* px = xT + (long)d * SS;
    bf16* pc = ctx + (long)d * SS;

    float phi_c = 0.f, mr_c = 0.f, mi_c = 0.f;
    for (int tchunk = 0; tchunk < SS / 64; tchunk++) {
        const int s = tchunk * 64 + lane;
        const float pos = (float)(s + 1);
        float w = __bfloat162float(po[s]) * sc * rsqrtf(pos);
        // inclusive wave scan of w
#pragma unroll
        for (int dlt = 1; dlt < 64; dlt <<= 1) {
            float v = __shfl_up(w, dlt, 64);
            if (lane >= dlt) w += v;
        }
        const float phi = phi_c + w;
        float sph, cph;
        sincosf(phi, &sph, &cph);
        const float xv = __bfloat162float(px[s]);
        const float cr = xv * cph, ci = xv * sph;
        float crs = cr, cis = ci;
#pragma unroll
        for (int dlt = 1; dlt < 64; dlt <<= 1) {
            float v1 = __shfl_up(crs, dlt, 64);
            float v2 = __shfl_up(cis, dlt, 64);
            if (lane >= dlt) { crs += v1; cis += v2; }
        }
        const float invp = 1.0f / pos;
        const float mr = (mr_c + crs) * invp;
        const float mi = (mi_c + cis) * invp;
        const float rr = mr * cph + mi * sph;
        const float ri = mi * cph - mr * sph;
        pc[s] = __float2bfloat16(cr);
        pc[(long)DD * SS + s] = __float2bfloat16(ci);
        pc[2L * DD * SS + s] = __float2bfloat16(rr);
        pc[3L * DD * SS + s] = __float2bfloat16(ri);
        phi_c += __shfl(w, 63, 64);
        mr_c += __shfl(crs, 63, 64);
        mi_c += __shfl(cis, 63, 64);
    }
}

// ---------------- per-s LN stats over f (split-f + atomics), per batch ----------------
__global__ void zero_f32(float* p, int n) {
    int i = blockIdx.x * 256 + threadIdx.x;
    if (i < n) p[i] = 0.f;
}

__global__ void stats_kernel(const bf16* __restrict__ ctx, float* __restrict__ sums,
                             float* __restrict__ sqs) {
    const int s = blockIdx.x * 256 + threadIdx.x;  // 0..S-1
    const int f0 = blockIdx.y * 512;
    const bf16* p = ctx + (long)f0 * SS + s;
    float sm = 0.f, sq = 0.f;
    for (int f = 0; f < 512; f++) {
        float v = __bfloat162float(p[(long)f * SS]);
        sm += v;
        sq += v * v;
    }
    atomicAdd(&sums[s], sm);
    atomicAdd(&sqs[s], sq);
}

// ---------------- LayerNorm + transpose back to s-major bf16 (per batch) ----------------
__global__ void lnt_kernel(const bf16* __restrict__ ctx, const float* __restrict__ sums,
                           const float* __restrict__ sqs, const float* __restrict__ gamma,
                           const float* __restrict__ beta, bf16* __restrict__ hln) {
    __shared__ float tl[64][65];
    const int f0 = blockIdx.y * 64, s0 = blockIdx.x * 64;
    const int tr = threadIdx.x >> 6, tc = threadIdx.x & 63;
    const bf16* ip = ctx + (long)f0 * SS + s0;
#pragma unroll
    for (int k = 0; k < 16; k++) {
        int fi = k * 4 + tr;
        tl[fi][tc] = __bfloat162float(ip[(long)fi * SS + tc]);
    }
    __syncthreads();
#pragma unroll
    for (int k = 0; k < 16; k++) {
        const int si = k * 4 + tr;
        const int s = s0 + si;
        const float mu = sums[s] * (1.0f / FD);
        const float var = sqs[s] * (1.0f / FD) - mu * mu;
        const float is = rsqrtf(var + 1e-5f);
        const int f = f0 + tc;
        const float v = (tl[tc][si] - mu) * is * gamma[f] + beta[f];
        hln[(long)s * FD + f] = __float2bfloat16(v);
    }
}

// ---------------- launch ----------------
extern "C" void kernel_launch(void* const* d_in, const int* in_sizes, int n_in,
                              void* d_out, int out_size, void* d_ws, size_t ws_size,
                              hipStream_t stream)
{
    const float* x = (const float*)d_in[0];
    const float* Wo = (const float*)d_in[1];
    const float* bo = (const float*)d_in[2];
    const float* lsc = (const float*)d_in[3];
    const float* gam = (const float*)d_in[4];
    const float* bet = (const float*)d_in[5];
    const float* W1 = (const float*)d_in[6];
    const float* b1 = (const float*)d_in[7];
    const float* W2 = (const float*)d_in[8];
    const float* b2 = (const float*)d_in[9];

    char* ws = (char*)d_ws;
    const size_t MB = 1024 * 1024;

    // Adaptive batching group size g, selected by available workspace.
    // g=4 peak: 23 + 128(hln) + 64(h1 over ctx/scratch) = 215 MB  (thr 220)
    // g=2 peak: 23 + 64 + 32(ctx) + 24(scratch)         = 143 MB  (thr 150)
    // g=1 peak: 23 + 32(hln over scratch) + 32(ctx)     =  87 MB  (known-good)
    int g;
    if (ws_size >= 220 * MB) g = 4;
    else if (ws_size >= 150 * MB) g = 2;
    else g = 1;

    // Persistent across batches:
    bf16* W1T = (bf16*)(ws + 0);           // 16 MB  (2048 x 4096)
    bf16* W2T = (bf16*)(ws + 16 * MB);     //  4 MB  (1024 x 2048)
    bf16* WoT = (bf16*)(ws + 20 * MB);     //  2 MB  (1024 x 1024)
    float* sums = (float*)(ws + 22 * MB);  // 16 KB
    float* sqs = sums + SS;                // 16 KB
    char* base = ws + 23 * MB;

    bf16 *hln, *ctx, *xb, *omT, *xT, *h1;
    if (g == 1) {
        // hln overlaps the per-batch scratch (xb/omT/xT all dead before lnt writes hln)
        hln = (bf16*)base;               // 32 MB [0,32)
        xb  = (bf16*)base;               //  8 MB [0,8)
        omT = (bf16*)(base + 8 * MB);    //  8 MB [8,16)
        xT  = (bf16*)(base + 16 * MB);   //  8 MB [16,24)
        ctx = (bf16*)(base + 32 * MB);   // 32 MB [32,64)
        h1  = ctx;                       // 16 MB aliases ctx (dead after lnt)
    } else {
        // hln_j must survive preprocessing of later batches in the group: no overlap.
        hln = (bf16*)base;                         // g*32 MB
        ctx = (bf16*)(base + (size_t)g * 32 * MB); // 32 MB
        xb  = (bf16*)((char*)ctx + 32 * MB);       //  8 MB
        omT = (bf16*)((char*)ctx + 40 * MB);       //  8 MB
        xT  = (bf16*)((char*)ctx + 48 * MB);       //  8 MB
        h1  = ctx;  // g*16 MB spanning ctx+scratch (+8 MB beyond for g=4), all dead by GEMM2
    }

    // Weight conversions (once per call; ws is re-poisoned before every call)
    transpose_f32_bf16<<<dim3(DD / 64, DD / 64), 256, 0, stream>>>(Wo, WoT, DD, DD);
    transpose_f32_bf16<<<dim3(GDIM / 64, FD / 64), 256, 0, stream>>>(W1, W1T, FD, GDIM);
    transpose_f32_bf16<<<dim3(DD / 64, GDIM / 64), 256, 0, stream>>>(W2, W2T, GDIM, DD);

    for (int b0 = 0; b0 < BB; b0 += g) {
        for (int j = 0; j < g; j++) {
            const int b = b0 + j;
            const float* xb_f32 = x + (long)b * SD;
            bf16* hln_b = hln + (long)j * SS * FD;

            conv_bf16<<<(int)(SD / 1024), 256, 0, stream>>>(xb_f32, xb, SD);
            transpose_f32_bf16<<<dim3(DD / 64, SS / 64), 256, 0, stream>>>(xb_f32, xT, SS, DD);

            // GEMM1: omega^T = Wo^T (1024x1024) * x^T  (A=WoT, BT=xb)
            gemm_bt<0><<<dim3(SS / 128, DD / 128), 256, 0, stream>>>(
                WoT, xb, omT, bo, nullptr, DD, SS, DD);

            // phase scan + complex memory -> ctx (4D, S)
            scan_kernel<<<DD / 4, 256, 0, stream>>>(omT, xT, lsc, ctx);

            // LN stats over f
            zero_f32<<<(2 * SS + 255) / 256, 256, 0, stream>>>(sums, 2 * SS);
            stats_kernel<<<dim3(SS / 256, FD / 512), 256, 0, stream>>>(ctx, sums, sqs);

            // LN + transpose to s-major bf16
            lnt_kernel<<<dim3(SS / 64, FD / 64), 256, 0, stream>>>(ctx, sums, sqs, gam, bet, hln_b);
        }

        // Batched GEMM2 over the group: h1 = gelu(hln * W1 + b1), M = g*S rows
        gemm_bt<1><<<dim3(GDIM / 128, g * SS / 128), 256, 0, stream>>>(
            hln, W1T, h1, b1, nullptr, g * SS, GDIM, FD);

        // Batched GEMM3: out = x + h1 * W2 + b2, fp32 out
        gemm_bt<2><<<dim3(DD / 128, g * SS / 128), 256, 0, stream>>>(
            h1, W2T, (float*)d_out + (long)b0 * SD, b2, x + (long)b0 * SD, g * SS, DD, GDIM);
    }
}

// Round 4
// 1073.273 us; speedup vs baseline: 1.2620x; 1.1336x over previous
//
#include <hip/hip_runtime.h>
#include <hip/hip_bf16.h>
#include <math.h>

typedef __hip_bfloat16 bf16;
typedef __attribute__((ext_vector_type(8))) short bf16x8;
typedef __attribute__((ext_vector_type(4))) float f32x4;

static constexpr int DD = 1024;    // D
static constexpr int BB = 4;       // batch
static constexpr int SS = 4096;    // seq
static constexpr int FD = 4096;    // 4D
static constexpr int GDIM = 2048;  // 2D
static constexpr long SD = (long)SS * DD;  // per-batch x elements (4M)

// ---------------- async global->LDS (16B per lane) ----------------
__device__ __forceinline__ void gl2lds16(const bf16* g, bf16* l) {
    __builtin_amdgcn_global_load_lds(
        (const __attribute__((address_space(1))) void*)g,
        (__attribute__((address_space(3))) void*)l, 16, 0, 0);
}

// ---------------- GEMM: C[M,N] = A[M,K] * BT[N,K]^T, all bf16 in ----------------
// z-batched via strides. Panel swizzle: gridDim.y must be a multiple of 8.
// EPI 0: +bias[row], store bf16     (GEMM1)
// EPI 1: +bias[col], gelu, bf16     (GEMM2)
// EPI 2: +bias[col]+X[row,col], f32 (GEMM3 + residual)
template <int EPI>
__global__ __launch_bounds__(256) void gemm_bt(
    const bf16* __restrict__ A, const bf16* __restrict__ BT, void* __restrict__ Cp,
    const float* __restrict__ bias, const float* __restrict__ Xadd,
    int M, int N, int K, long strA, long strBT, long strC)
{
    __shared__ __align__(16) bf16 As[128 * 32];
    __shared__ __align__(16) bf16 Bs[128 * 32];
    const int t = threadIdx.x;
    const int l = t & 63, wv = t >> 6;

    // panel swizzle: 8 row-blocks x all col-blocks per panel (A 8MB + B-slice L2-hot)
    const int lin = blockIdx.y * gridDim.x + blockIdx.x;
    const int per = gridDim.x << 3;
    const int p = lin / per, r = lin - p * per;
    const long m0 = (long)(p * 8 + (r & 7)) * 128;
    const long n0 = (long)(r >> 3) * 128;

    A += (long)blockIdx.z * strA;
    BT += (long)blockIdx.z * strBT;

    // staging: each wave stages 16 rows per call, 2 calls per matrix (rows +0 / +64)
    const int rowOff = wv * 16 + (l >> 2);               // 0..63
    const int kgrp = (l & 3) ^ ((l >> 2) & 3);           // XOR swizzle on k-chunk
    const bf16* pa = A + (m0 + rowOff) * (long)K + kgrp * 8;
    const bf16* pa2 = pa + 64L * K;
    const bf16* pb = BT + (n0 + rowOff) * (long)K + kgrp * 8;
    const bf16* pb2 = pb + 64L * K;
    bf16* la = &As[(wv * 16) * 32];
    bf16* la2 = &As[(wv * 16 + 64) * 32];
    bf16* lb = &Bs[(wv * 16) * 32];
    bf16* lb2 = &Bs[(wv * 16 + 64) * 32];

    f32x4 acc[4][4];
#pragma unroll
    for (int i = 0; i < 4; i++)
#pragma unroll
        for (int j = 0; j < 4; j++) acc[i][j] = (f32x4){0.f, 0.f, 0.f, 0.f};

    const int wr = wv >> 1, wc = wv & 1;
    const int fm = l & 15, q = l >> 4;
    const int sw = (q ^ (fm & 3)) << 3;  // swizzled chunk offset (elements)

    for (int k0 = 0; k0 < K; k0 += 32) {
        gl2lds16(pa, la);
        gl2lds16(pa2, la2);
        gl2lds16(pb, lb);
        gl2lds16(pb2, lb2);
        pa += 32; pa2 += 32; pb += 32; pb2 += 32;
        __syncthreads();
        bf16x8 af[4], bfr[4];
#pragma unroll
        for (int i = 0; i < 4; i++)
            af[i] = *(const bf16x8*)&As[(wr * 64 + i * 16 + fm) * 32 + sw];
#pragma unroll
        for (int j = 0; j < 4; j++)
            bfr[j] = *(const bf16x8*)&Bs[(wc * 64 + j * 16 + fm) * 32 + sw];
#pragma unroll
        for (int i = 0; i < 4; i++)
#pragma unroll
            for (int j = 0; j < 4; j++)
                acc[i][j] = __builtin_amdgcn_mfma_f32_16x16x32_bf16(af[i], bfr[j], acc[i][j], 0, 0, 0);
        __syncthreads();
    }

    const long cb = (long)blockIdx.z * strC;
#pragma unroll
    for (int i = 0; i < 4; i++) {
#pragma unroll
        for (int j = 0; j < 4; j++) {
            const long col = n0 + wc * 64 + j * 16 + fm;
            const long rB = m0 + wr * 64 + i * 16 + q * 4;
#pragma unroll
            for (int r2 = 0; r2 < 4; r2++) {
                const long row = rB + r2;
                float v = acc[i][j][r2];
                if (EPI == 0) {
                    v += bias[row];
                    ((bf16*)Cp)[cb + row * (long)N + col] = __float2bfloat16(v);
                } else if (EPI == 1) {
                    v += bias[col];
                    v = 0.5f * v * (1.0f + erff(v * 0.70710678118654752f));
                    ((bf16*)Cp)[cb + row * (long)N + col] = __float2bfloat16(v);
                } else {
                    v += bias[col] + Xadd[row * (long)N + col];
                    ((float*)Cp)[cb + row * (long)N + col] = v;
                }
            }
        }
    }
}

// ---------------- fp32 -> bf16 straight convert ----------------
__global__ void conv_bf16(const float* __restrict__ in, bf16* __restrict__ out, long n) {
    long i = ((long)blockIdx.x * 256 + threadIdx.x) * 4;
    if (i >= n) return;
    const float4 v = *(const float4*)(in + i);
    bf16 o[4] = {__float2bfloat16(v.x), __float2bfloat16(v.y),
                 __float2bfloat16(v.z), __float2bfloat16(v.w)};
    *(uint2*)(out + i) = *(uint2*)o;
}

// ---------------- fp32 (R x C) -> bf16 (C x R) transpose, z-batched ----------------
__global__ void transpose_f32_bf16(const float* __restrict__ in, bf16* __restrict__ out,
                                   int R, int C, long inStr, long outStr) {
    __shared__ float tl[64][65];
    const float* ip = in + (long)blockIdx.z * inStr;
    bf16* op = out + (long)blockIdx.z * outStr;
    const int r0 = blockIdx.y * 64, c0 = blockIdx.x * 64;
    const int tr = threadIdx.x >> 6, tc = threadIdx.x & 63;
#pragma unroll
    for (int k = 0; k < 16; k++) {
        int r = k * 4 + tr;
        tl[r][tc] = ip[(long)(r0 + r) * C + c0 + tc];
    }
    __syncthreads();
#pragma unroll
    for (int k = 0; k < 16; k++) {
        int r = k * 4 + tr;
        op[(long)(c0 + r) * R + r0 + tc] = __float2bfloat16(tl[tc][r]);
    }
}

// ---------------- serial part: phase cumsum + complex memory, one wave per (z,d) ----------------
__global__ __launch_bounds__(256) void scan_kernel(
    const bf16* __restrict__ omegaT, const bf16* __restrict__ xT,
    const float* __restrict__ log_scale, bf16* __restrict__ ctx,
    long strIn, long strCtx)
{
    const int d = blockIdx.x * 4 + (threadIdx.x >> 6);
    const int lane = threadIdx.x & 63;
    const float sc = expf(log_scale[d]);
    const bf16* po = omegaT + (long)blockIdx.z * strIn + (long)d * SS;
    const bf16* px = xT + (long)blockIdx.z * strIn + (long)d * SS;
    bf16* pc = ctx + (long)blockIdx.z * strCtx + (long)d * SS;

    float phi_c = 0.f, mr_c = 0.f, mi_c = 0.f;
    for (int tchunk = 0; tchunk < SS / 64; tchunk++) {
        const int s = tchunk * 64 + lane;
        const float pos = (float)(s + 1);
        float w = __bfloat162float(po[s]) * sc * rsqrtf(pos);
#pragma unroll
        for (int dlt = 1; dlt < 64; dlt <<= 1) {
            float v = __shfl_up(w, dlt, 64);
            if (lane >= dlt) w += v;
        }
        const float phi = phi_c + w;
        float sph, cph;
        sincosf(phi, &sph, &cph);
        const float xv = __bfloat162float(px[s]);
        const float cr = xv * cph, ci = xv * sph;
        float crs = cr, cis = ci;
#pragma unroll
        for (int dlt = 1; dlt < 64; dlt <<= 1) {
            float v1 = __shfl_up(crs, dlt, 64);
            float v2 = __shfl_up(cis, dlt, 64);
            if (lane >= dlt) { crs += v1; cis += v2; }
        }
        const float invp = 1.0f / pos;
        const float mr = (mr_c + crs) * invp;
        const float mi = (mi_c + cis) * invp;
        const float rr = mr * cph + mi * sph;
        const float ri = mi * cph - mr * sph;
        pc[s] = __float2bfloat16(cr);
        pc[(long)DD * SS + s] = __float2bfloat16(ci);
        pc[2L * DD * SS + s] = __float2bfloat16(rr);
        pc[3L * DD * SS + s] = __float2bfloat16(ri);
        phi_c += __shfl(w, 63, 64);
        mr_c += __shfl(crs, 63, 64);
        mi_c += __shfl(cis, 63, 64);
    }
}

// ---------------- per-s LN stats over f (split-f + atomics), z-batched ----------------
__global__ void zero_f32(float* p, int n) {
    int i = blockIdx.x * 256 + threadIdx.x;
    if (i < n) p[i] = 0.f;
}

__global__ void stats_kernel(const bf16* __restrict__ ctx, float* __restrict__ sums,
                             float* __restrict__ sqs) {
    const int s = blockIdx.x * 256 + threadIdx.x;  // 0..S-1
    const int f0 = blockIdx.y * 512;
    const int z = blockIdx.z;
    const bf16* p = ctx + (long)z * 4 * SD + (long)f0 * SS + s;
    float sm = 0.f, sq = 0.f;
    for (int f = 0; f < 512; f++) {
        float v = __bfloat162float(p[(long)f * SS]);
        sm += v;
        sq += v * v;
    }
    atomicAdd(&sums[z * SS + s], sm);
    atomicAdd(&sqs[z * SS + s], sq);
}

// ---------------- LayerNorm + transpose back to s-major bf16, z-batched ----------------
__global__ void lnt_kernel(const bf16* __restrict__ ctx, const float* __restrict__ sums,
                           const float* __restrict__ sqs, const float* __restrict__ gamma,
                           const float* __restrict__ beta, bf16* __restrict__ hln) {
    __shared__ float tl[64][65];
    const int f0 = blockIdx.y * 64, s0 = blockIdx.x * 64;
    const int z = blockIdx.z;
    const int tr = threadIdx.x >> 6, tc = threadIdx.x & 63;
    const bf16* ip = ctx + (long)z * 4 * SD + (long)f0 * SS + s0;
#pragma unroll
    for (int k = 0; k < 16; k++) {
        int fi = k * 4 + tr;
        tl[fi][tc] = __bfloat162float(ip[(long)fi * SS + tc]);
    }
    __syncthreads();
#pragma unroll
    for (int k = 0; k < 16; k++) {
        const int si = k * 4 + tr;
        const int s = s0 + si;
        const float mu = sums[z * SS + s] * (1.0f / FD);
        const float var = sqs[z * SS + s] * (1.0f / FD) - mu * mu;
        const float is = rsqrtf(var + 1e-5f);
        const int f = f0 + tc;
        const float v = (tl[tc][si] - mu) * is * gamma[f] + beta[f];
        hln[(long)z * SS * FD + (long)s * FD + f] = __float2bfloat16(v);
    }
}

// ---------------- launch ----------------
extern "C" void kernel_launch(void* const* d_in, const int* in_sizes, int n_in,
                              void* d_out, int out_size, void* d_ws, size_t ws_size,
                              hipStream_t stream)
{
    const float* x = (const float*)d_in[0];
    const float* Wo = (const float*)d_in[1];
    const float* bo = (const float*)d_in[2];
    const float* lsc = (const float*)d_in[3];
    const float* gam = (const float*)d_in[4];
    const float* bet = (const float*)d_in[5];
    const float* W1 = (const float*)d_in[6];
    const float* b1 = (const float*)d_in[7];
    const float* W2 = (const float*)d_in[8];
    const float* b2 = (const float*)d_in[9];

    char* ws = (char*)d_ws;
    const size_t MB = 1024 * 1024;

    // Persistent weights:
    bf16* W1T = (bf16*)(ws + 0);           // 16 MB  (2048 x 4096)
    bf16* W2T = (bf16*)(ws + 16 * MB);     //  4 MB  (1024 x 2048)
    bf16* WoT = (bf16*)(ws + 20 * MB);     //  2 MB  (1024 x 1024)
    float* sums = (float*)(ws + 22 * MB);  // 2*SS floats
    float* sqs = sums + 2 * SS;            // 2*SS floats

    transpose_f32_bf16<<<dim3(DD / 64, DD / 64, 1), 256, 0, stream>>>(Wo, WoT, DD, DD, 0, 0);
    transpose_f32_bf16<<<dim3(GDIM / 64, FD / 64, 1), 256, 0, stream>>>(W1, W1T, FD, GDIM, 0, 0);
    transpose_f32_bf16<<<dim3(DD / 64, GDIM / 64, 1), 256, 0, stream>>>(W2, W2T, GDIM, DD, 0, 0);

    if (ws_size >= 220 * MB) {
        // ---- main path: fully batched pre/GEMM1, group-of-2 scan/LN/GEMM2/3. Peak 215 MB ----
        bf16* xT   = (bf16*)(ws + 23 * MB);   // 32 MB [23,55)   (b,d,s), alive through both scans
        bf16* omT  = (bf16*)(ws + 55 * MB);   // 32 MB [55,87)   (b,d,s), alive through both scans
        bf16* xb   = (bf16*)(ws + 87 * MB);   // 32 MB [87,119)  (b,s,d), dead after GEMM1
        bf16* hln2 = (bf16*)(ws + 87 * MB);   // 64 MB [87,151)  overlays dead xb
        bf16* ctx2 = (bf16*)(ws + 151 * MB);  // 64 MB [151,215) per group
        bf16* h1   = (bf16*)(ws + 151 * MB);  // 32 MB overlays dead ctx2 of same group

        conv_bf16<<<(int)(BB * SD / 1024), 256, 0, stream>>>(x, xb, BB * SD);
        transpose_f32_bf16<<<dim3(DD / 64, SS / 64, BB), 256, 0, stream>>>(x, xT, SS, DD, SD, SD);

        // GEMM1 batched over 4: omega^T[b] = Wo^T * x[b]^T
        gemm_bt<0><<<dim3(SS / 128, DD / 128, BB), 256, 0, stream>>>(
            WoT, xb, omT, bo, nullptr, DD, SS, DD, 0L, SD, SD);

        for (int b0 = 0; b0 < BB; b0 += 2) {
            scan_kernel<<<dim3(DD / 4, 1, 2), 256, 0, stream>>>(
                omT + (long)b0 * SD, xT + (long)b0 * SD, lsc, ctx2, SD, 4 * SD);

            zero_f32<<<(4 * SS + 255) / 256, 256, 0, stream>>>(sums, 4 * SS);
            stats_kernel<<<dim3(SS / 256, FD / 512, 2), 256, 0, stream>>>(ctx2, sums, sqs);
            lnt_kernel<<<dim3(SS / 64, FD / 64, 2), 256, 0, stream>>>(ctx2, sums, sqs, gam, bet, hln2);

            // GEMM2 (M = 2*S = 8192): h1 = gelu(hln2 * W1 + b1)
            gemm_bt<1><<<dim3(GDIM / 128, 2 * SS / 128, 1), 256, 0, stream>>>(
                hln2, W1T, h1, b1, nullptr, 2 * SS, GDIM, FD, 0L, 0L, 0L);

            // GEMM3: out = x + h1 * W2 + b2
            gemm_bt<2><<<dim3(DD / 128, 2 * SS / 128, 1), 256, 0, stream>>>(
                h1, W2T, (float*)d_out + (long)b0 * SD, b2, x + (long)b0 * SD,
                2 * SS, DD, GDIM, 0L, 0L, 0L);
        }
    } else {
        // ---- fallback: known-good 87 MB per-batch path ----
        char* base = ws + 23 * MB;
        bf16* hln = (bf16*)base;               // 32 MB, overlays scratch
        bf16* xb  = (bf16*)base;               //  8 MB
        bf16* omT = (bf16*)(base + 8 * MB);    //  8 MB
        bf16* xT  = (bf16*)(base + 16 * MB);   //  8 MB
        bf16* ctx = (bf16*)(base + 32 * MB);   // 32 MB
        bf16* h1  = ctx;                       // 16 MB

        for (int b = 0; b < BB; b++) {
            const float* xbf = x + (long)b * SD;
            conv_bf16<<<(int)(SD / 1024), 256, 0, stream>>>(xbf, xb, SD);
            transpose_f32_bf16<<<dim3(DD / 64, SS / 64, 1), 256, 0, stream>>>(xbf, xT, SS, DD, 0, 0);
            gemm_bt<0><<<dim3(SS / 128, DD / 128, 1), 256, 0, stream>>>(
                WoT, xb, omT, bo, nullptr, DD, SS, DD, 0L, 0L, 0L);
            scan_kernel<<<dim3(DD / 4, 1, 1), 256, 0, stream>>>(omT, xT, lsc, ctx, 0, 0);
            zero_f32<<<(2 * SS + 255) / 256, 256, 0, stream>>>(sums, 2 * SS);
            stats_kernel<<<dim3(SS / 256, FD / 512, 1), 256, 0, stream>>>(ctx, sums, sqs);
            lnt_kernel<<<dim3(SS / 64, FD / 64, 1), 256, 0, stream>>>(ctx, sums, sqs, gam, bet, hln);
            gemm_bt<1><<<dim3(GDIM / 128, SS / 128, 1), 256, 0, stream>>>(
                hln, W1T, h1, b1, nullptr, SS, GDIM, FD, 0L, 0L, 0L);
            gemm_bt<2><<<dim3(DD / 128, SS / 128, 1), 256, 0, stream>>>(
                h1, W2T, (float*)d_out + (long)b * SD, b2, xbf, SS, DD, GDIM, 0L, 0L, 0L);
        }
    }
}

// Round 5
// 842.565 us; speedup vs baseline: 1.6076x; 1.2738x over previous
//
#include <hip/hip_runtime.h>
#include <hip/hip_bf16.h>
#include <math.h>

typedef __hip_bfloat16 bf16;
typedef __attribute__((ext_vector_type(8))) short bf16x8;
typedef __attribute__((ext_vector_type(4))) float f32x4;

static constexpr int DD = 1024;    // D
static constexpr int BB = 4;       // batch
static constexpr int SS = 4096;    // seq
static constexpr int FD = 4096;    // 4D
static constexpr int GDIM = 2048;  // 2D
static constexpr long SD = (long)SS * DD;   // per-batch x elements (4M)
static constexpr long SD4 = 4 * SD;         // per-batch ctx elements

// ---------------- async global->LDS (16B per lane) ----------------
__device__ __forceinline__ void gl2lds16(const bf16* g, bf16* l) {
    __builtin_amdgcn_global_load_lds(
        (const __attribute__((address_space(1))) void*)g,
        (__attribute__((address_space(3))) void*)l, 16, 0, 0);
}

// ---------------- GEMM: C[M,N] = A[M,K] * BT[N,K]^T, all bf16 in ----------------
// z-batched via strides. Panel swizzle: gridDim.y must be a multiple of 8.
// EPI 0: +bias[row], store bf16     (GEMM1)
// EPI 1: +bias[col], gelu, bf16     (GEMM2)  [launch_bounds 4: force 4 blocks/CU]
// EPI 2: +bias[col]+X[row,col], f32 (GEMM3 + residual)
template <int EPI>
__global__ __launch_bounds__(256, EPI == 1 ? 4 : 1) void gemm_bt(
    const bf16* __restrict__ A, const bf16* __restrict__ BT, void* __restrict__ Cp,
    const float* __restrict__ bias, const float* __restrict__ Xadd,
    int M, int N, int K, long strA, long strBT, long strC)
{
    __shared__ __align__(16) bf16 As[128 * 32];
    __shared__ __align__(16) bf16 Bs[128 * 32];
    const int t = threadIdx.x;
    const int l = t & 63, wv = t >> 6;

    // panel swizzle: 8 row-blocks x all col-blocks per panel
    const int lin = blockIdx.y * gridDim.x + blockIdx.x;
    const int per = gridDim.x << 3;
    const int p = lin / per, r = lin - p * per;
    const long m0 = (long)(p * 8 + (r & 7)) * 128;
    const long n0 = (long)(r >> 3) * 128;

    A += (long)blockIdx.z * strA;
    BT += (long)blockIdx.z * strBT;

    const int rowOff = wv * 16 + (l >> 2);               // 0..63
    const int kgrp = (l & 3) ^ ((l >> 2) & 3);           // XOR swizzle on k-chunk
    const bf16* pa = A + (m0 + rowOff) * (long)K + kgrp * 8;
    const bf16* pa2 = pa + 64L * K;
    const bf16* pb = BT + (n0 + rowOff) * (long)K + kgrp * 8;
    const bf16* pb2 = pb + 64L * K;
    bf16* la = &As[(wv * 16) * 32];
    bf16* la2 = &As[(wv * 16 + 64) * 32];
    bf16* lb = &Bs[(wv * 16) * 32];
    bf16* lb2 = &Bs[(wv * 16 + 64) * 32];

    f32x4 acc[4][4];
#pragma unroll
    for (int i = 0; i < 4; i++)
#pragma unroll
        for (int j = 0; j < 4; j++) acc[i][j] = (f32x4){0.f, 0.f, 0.f, 0.f};

    const int wr = wv >> 1, wc = wv & 1;
    const int fm = l & 15, q = l >> 4;
    const int sw = (q ^ (fm & 3)) << 3;

    for (int k0 = 0; k0 < K; k0 += 32) {
        gl2lds16(pa, la);
        gl2lds16(pa2, la2);
        gl2lds16(pb, lb);
        gl2lds16(pb2, lb2);
        pa += 32; pa2 += 32; pb += 32; pb2 += 32;
        __syncthreads();
        bf16x8 af[4], bfr[4];
#pragma unroll
        for (int i = 0; i < 4; i++)
            af[i] = *(const bf16x8*)&As[(wr * 64 + i * 16 + fm) * 32 + sw];
#pragma unroll
        for (int j = 0; j < 4; j++)
            bfr[j] = *(const bf16x8*)&Bs[(wc * 64 + j * 16 + fm) * 32 + sw];
#pragma unroll
        for (int i = 0; i < 4; i++)
#pragma unroll
            for (int j = 0; j < 4; j++)
                acc[i][j] = __builtin_amdgcn_mfma_f32_16x16x32_bf16(af[i], bfr[j], acc[i][j], 0, 0, 0);
        __syncthreads();
    }

    const long cb = (long)blockIdx.z * strC;
#pragma unroll
    for (int i = 0; i < 4; i++) {
#pragma unroll
        for (int j = 0; j < 4; j++) {
            const long col = n0 + wc * 64 + j * 16 + fm;
            const long rB = m0 + wr * 64 + i * 16 + q * 4;
#pragma unroll
            for (int r2 = 0; r2 < 4; r2++) {
                const long row = rB + r2;
                float v = acc[i][j][r2];
                if (EPI == 0) {
                    v += bias[row];
                    ((bf16*)Cp)[cb + row * (long)N + col] = __float2bfloat16(v);
                } else if (EPI == 1) {
                    v += bias[col];
                    v = 0.5f * v * (1.0f + erff(v * 0.70710678118654752f));
                    ((bf16*)Cp)[cb + row * (long)N + col] = __float2bfloat16(v);
                } else {
                    v += bias[col] + Xadd[row * (long)N + col];
                    ((float*)Cp)[cb + row * (long)N + col] = v;
                }
            }
        }
    }
}

// ---------------- fp32 -> bf16 straight convert ----------------
__global__ void conv_bf16(const float* __restrict__ in, bf16* __restrict__ out, long n) {
    long i = ((long)blockIdx.x * 256 + threadIdx.x) * 4;
    if (i >= n) return;
    const float4 v = *(const float4*)(in + i);
    bf16 o[4] = {__float2bfloat16(v.x), __float2bfloat16(v.y),
                 __float2bfloat16(v.z), __float2bfloat16(v.w)};
    *(uint2*)(out + i) = *(uint2*)o;
}

// ---------------- fp32 (R x C) -> bf16 (C x R) transpose, z-batched ----------------
__global__ void transpose_f32_bf16(const float* __restrict__ in, bf16* __restrict__ out,
                                   int R, int C, long inStr, long outStr) {
    __shared__ float tl[64][65];
    const float* ip = in + (long)blockIdx.z * inStr;
    bf16* op = out + (long)blockIdx.z * outStr;
    const int r0 = blockIdx.y * 64, c0 = blockIdx.x * 64;
    const int tr = threadIdx.x >> 6, tc = threadIdx.x & 63;
#pragma unroll
    for (int k = 0; k < 16; k++) {
        int r = k * 4 + tr;
        tl[r][tc] = ip[(long)(r0 + r) * C + c0 + tc];
    }
    __syncthreads();
#pragma unroll
    for (int k = 0; k < 16; k++) {
        int r = k * 4 + tr;
        op[(long)(c0 + r) * R + r0 + tc] = __float2bfloat16(tl[tc][r]);
    }
}

// ---------------- serial part: phase cumsum + complex memory, one wave per (z,d) ----------------
__global__ __launch_bounds__(256) void scan_kernel(
    const bf16* __restrict__ omegaT, const bf16* __restrict__ xT,
    const float* __restrict__ log_scale, bf16* __restrict__ ctx,
    long strIn, long strCtx)
{
    const int d = blockIdx.x * 4 + (threadIdx.x >> 6);
    const int lane = threadIdx.x & 63;
    const float sc = expf(log_scale[d]);
    const bf16* po = omegaT + (long)blockIdx.z * strIn + (long)d * SS;
    const bf16* px = xT + (long)blockIdx.z * strIn + (long)d * SS;
    bf16* pc = ctx + (long)blockIdx.z * strCtx + (long)d * SS;

    float phi_c = 0.f, mr_c = 0.f, mi_c = 0.f;
    for (int tchunk = 0; tchunk < SS / 64; tchunk++) {
        const int s = tchunk * 64 + lane;
        const float pos = (float)(s + 1);
        float w = __bfloat162float(po[s]) * sc * rsqrtf(pos);
#pragma unroll
        for (int dlt = 1; dlt < 64; dlt <<= 1) {
            float v = __shfl_up(w, dlt, 64);
            if (lane >= dlt) w += v;
        }
        const float phi = phi_c + w;
        float sph, cph;
        sincosf(phi, &sph, &cph);
        const float xv = __bfloat162float(px[s]);
        const float cr = xv * cph, ci = xv * sph;
        float crs = cr, cis = ci;
#pragma unroll
        for (int dlt = 1; dlt < 64; dlt <<= 1) {
            float v1 = __shfl_up(crs, dlt, 64);
            float v2 = __shfl_up(cis, dlt, 64);
            if (lane >= dlt) { crs += v1; cis += v2; }
        }
        const float invp = 1.0f / pos;
        const float mr = (mr_c + crs) * invp;
        const float mi = (mi_c + cis) * invp;
        const float rr = mr * cph + mi * sph;
        const float ri = mi * cph - mr * sph;
        pc[s] = __float2bfloat16(cr);
        pc[(long)DD * SS + s] = __float2bfloat16(ci);
        pc[2L * DD * SS + s] = __float2bfloat16(rr);
        pc[3L * DD * SS + s] = __float2bfloat16(ri);
        phi_c += __shfl(w, 63, 64);
        mr_c += __shfl(crs, 63, 64);
        mi_c += __shfl(cis, 63, 64);
    }
}

// ---------------- per-s LN stats over f (split-f + atomics), z-batched ----------------
__global__ void zero_f32(float* p, int n) {
    int i = blockIdx.x * 256 + threadIdx.x;
    if (i < n) p[i] = 0.f;
}

__global__ void stats_kernel(const bf16* __restrict__ ctx, float* __restrict__ sums,
                             float* __restrict__ sqs) {
    const int s = blockIdx.x * 256 + threadIdx.x;  // 0..S-1
    const int f0 = blockIdx.y * 512;
    const int z = blockIdx.z;
    const bf16* p = ctx + (long)z * SD4 + (long)f0 * SS + s;
    float sm = 0.f, sq = 0.f;
    for (int f = 0; f < 512; f++) {
        float v = __bfloat162float(p[(long)f * SS]);
        sm += v;
        sq += v * v;
    }
    atomicAdd(&sums[z * SS + s], sm);
    atomicAdd(&sqs[z * SS + s], sq);
}

// ---------------- in-place LayerNorm + transpose (f,s)->(s,f), triangular pairs ----------------
// ctx is overwritten: on exit the same buffer holds hln in (s,f) layout.
// Block x = linear index over upper-triangle pairs (a<=b) of the 64x64 tile grid.
__global__ __launch_bounds__(256) void lnt_pair(
    bf16* __restrict__ ctx, const float* __restrict__ sums, const float* __restrict__ sqs,
    const float* __restrict__ gamma, const float* __restrict__ beta)
{
    __shared__ float tA[64][65];
    __shared__ float tB[64][65];
    const int z = blockIdx.z;
    // decode pair (a,b), a <= b, from linear index
    int rem = blockIdx.x, a = 0;
    for (int i = 0; i < 64; i++) {
        int cnt = 64 - i;
        if (rem < cnt) { a = i; break; }
        rem -= cnt;
    }
    const int b = a + rem;
    bf16* base = ctx + (long)z * SD4;
    const int tr = threadIdx.x >> 6, tc = threadIdx.x & 63;
    const float* sums_z = sums + z * SS;
    const float* sqs_z = sqs + z * SS;

#pragma unroll
    for (int k = 0; k < 16; k++) {
        int i = k * 4 + tr;
        tA[i][tc] = __bfloat162float(base[(long)(a * 64 + i) * SS + b * 64 + tc]);
    }
    if (a != b) {
#pragma unroll
        for (int k = 0; k < 16; k++) {
            int i = k * 4 + tr;
            tB[i][tc] = __bfloat162float(base[(long)(b * 64 + i) * SS + a * 64 + tc]);
        }
    }
    __syncthreads();

    // write region (b,a): hln[s=b*64+i][f=a*64+tc] = LN(tA[tc][i], row s, col f)
    {
        const float g = gamma[a * 64 + tc], be = beta[a * 64 + tc];
#pragma unroll
        for (int k = 0; k < 16; k++) {
            const int i = k * 4 + tr;
            const int s = b * 64 + i;
            const float mu = sums_z[s] * (1.0f / FD);
            const float var = sqs_z[s] * (1.0f / FD) - mu * mu;
            const float is = rsqrtf(var + 1e-5f);
            const float v = (tA[tc][i] - mu) * is * g + be;
            base[(long)s * FD + a * 64 + tc] = __float2bfloat16(v);
        }
    }
    if (a != b) {
        // write region (a,b): hln[s=a*64+i][f=b*64+tc] = LN(tB[tc][i], row s, col f)
        const float g = gamma[b * 64 + tc], be = beta[b * 64 + tc];
#pragma unroll
        for (int k = 0; k < 16; k++) {
            const int i = k * 4 + tr;
            const int s = a * 64 + i;
            const float mu = sums_z[s] * (1.0f / FD);
            const float var = sqs_z[s] * (1.0f / FD) - mu * mu;
            const float is = rsqrtf(var + 1e-5f);
            const float v = (tB[tc][i] - mu) * is * g + be;
            base[(long)s * FD + b * 64 + tc] = __float2bfloat16(v);
        }
    }
}

// ---------------- launch ----------------
extern "C" void kernel_launch(void* const* d_in, const int* in_sizes, int n_in,
                              void* d_out, int out_size, void* d_ws, size_t ws_size,
                              hipStream_t stream)
{
    const float* x = (const float*)d_in[0];
    const float* Wo = (const float*)d_in[1];
    const float* bo = (const float*)d_in[2];
    const float* lsc = (const float*)d_in[3];
    const float* gam = (const float*)d_in[4];
    const float* bet = (const float*)d_in[5];
    const float* W1 = (const float*)d_in[6];
    const float* b1 = (const float*)d_in[7];
    const float* W2 = (const float*)d_in[8];
    const float* b2 = (const float*)d_in[9];

    char* ws = (char*)d_ws;
    const size_t MB = 1024 * 1024;

    // Persistent weights:
    bf16* W1T = (bf16*)(ws + 0);           // 16 MB  (2048 x 4096)
    bf16* W2T = (bf16*)(ws + 16 * MB);     //  4 MB  (1024 x 2048)
    bf16* WoT = (bf16*)(ws + 20 * MB);     //  2 MB  (1024 x 1024)
    float* sums = (float*)(ws + 22 * MB);  // 4*SS floats (64 KB)
    float* sqs = sums + 4 * SS;            // 4*SS floats

    transpose_f32_bf16<<<dim3(DD / 64, DD / 64, 1), 256, 0, stream>>>(Wo, WoT, DD, DD, 0, 0);
    transpose_f32_bf16<<<dim3(GDIM / 64, FD / 64, 1), 256, 0, stream>>>(W1, W1T, FD, GDIM, 0, 0);
    transpose_f32_bf16<<<dim3(DD / 64, GDIM / 64, 1), 256, 0, stream>>>(W2, W2T, GDIM, DD, 0, 0);

    const int NPAIR = 64 * 65 / 2;  // 2080 tile-pairs per batch

    if (ws_size >= 220 * MB) {
        // ---- main path (peak 215 MB) ----
        // [23,55)  xT  32 MB (b,d,s)  — alive until scan done
        // [55,87)  omT 32 MB (b,d,s)  — alive until scan done
        // [87,215) ctx/hln 128 MB     — scan writes (f,s); lnt_pair converts in-place to (s,f)
        //          xb 32 MB at [87,119): dead after GEMM1, before scan writes ctx[b=0]
        // [23,87)  h1 64 MB           — after scan, overlays dead xT+omT
        bf16* xT  = (bf16*)(ws + 23 * MB);
        bf16* omT = (bf16*)(ws + 55 * MB);
        bf16* ctx = (bf16*)(ws + 87 * MB);
        bf16* xb  = (bf16*)(ws + 87 * MB);
        bf16* h1  = (bf16*)(ws + 23 * MB);

        conv_bf16<<<(int)(BB * SD / 1024), 256, 0, stream>>>(x, xb, BB * SD);
        transpose_f32_bf16<<<dim3(DD / 64, SS / 64, BB), 256, 0, stream>>>(x, xT, SS, DD, SD, SD);

        // GEMM1 batched over 4: omega^T[b] = Wo^T * x[b]^T
        gemm_bt<0><<<dim3(SS / 128, DD / 128, BB), 256, 0, stream>>>(
            WoT, xb, omT, bo, nullptr, DD, SS, DD, 0L, SD, SD);

        // phase scan, all 4 batches -> ctx (f,s)
        scan_kernel<<<dim3(DD / 4, 1, BB), 256, 0, stream>>>(omT, xT, lsc, ctx, SD, SD4);

        // LN stats
        zero_f32<<<(8 * SS + 255) / 256, 256, 0, stream>>>(sums, 8 * SS);
        stats_kernel<<<dim3(SS / 256, FD / 512, BB), 256, 0, stream>>>(ctx, sums, sqs);

        // in-place LN + transpose: ctx (f,s) -> hln (s,f)
        lnt_pair<<<dim3(NPAIR, 1, BB), 256, 0, stream>>>(ctx, sums, sqs, gam, bet);

        // GEMM2 (M = 16384): h1 = gelu(hln * W1 + b1)
        gemm_bt<1><<<dim3(GDIM / 128, BB * SS / 128, 1), 256, 0, stream>>>(
            ctx, W1T, h1, b1, nullptr, BB * SS, GDIM, FD, 0L, 0L, 0L);

        // GEMM3 (M = 16384): out = x + h1 * W2 + b2, fp32
        gemm_bt<2><<<dim3(DD / 128, BB * SS / 128, 1), 256, 0, stream>>>(
            h1, W2T, d_out, b2, x, BB * SS, DD, GDIM, 0L, 0L, 0L);
    } else {
        // ---- fallback: per-batch, peak 71 MB ----
        bf16* xb  = (bf16*)(ws + 23 * MB);  //  8 MB, dead after GEMM1 (ctx overlays)
        bf16* ctx = (bf16*)(ws + 23 * MB);  // 32 MB [23,55)
        bf16* omT = (bf16*)(ws + 55 * MB);  //  8 MB
        bf16* xT  = (bf16*)(ws + 63 * MB);  //  8 MB
        bf16* h1  = (bf16*)(ws + 55 * MB);  // 16 MB overlays omT+xT after scan

        for (int b = 0; b < BB; b++) {
            const float* xbf = x + (long)b * SD;
            conv_bf16<<<(int)(SD / 1024), 256, 0, stream>>>(xbf, xb, SD);
            transpose_f32_bf16<<<dim3(DD / 64, SS / 64, 1), 256, 0, stream>>>(xbf, xT, SS, DD, 0, 0);
            gemm_bt<0><<<dim3(SS / 128, DD / 128, 1), 256, 0, stream>>>(
                WoT, xb, omT, bo, nullptr, DD, SS, DD, 0L, 0L, 0L);
            scan_kernel<<<dim3(DD / 4, 1, 1), 256, 0, stream>>>(omT, xT, lsc, ctx, 0L, 0L);
            zero_f32<<<(2 * SS + 255) / 256, 256, 0, stream>>>(sums, 2 * SS);
            stats_kernel<<<dim3(SS / 256, FD / 512, 1), 256, 0, stream>>>(ctx, sums, sqs);
            lnt_pair<<<dim3(NPAIR, 1, 1), 256, 0, stream>>>(ctx, sums, sqs, gam, bet);
            gemm_bt<1><<<dim3(GDIM / 128, SS / 128, 1), 256, 0, stream>>>(
                ctx, W1T, h1, b1, nullptr, SS, GDIM, FD, 0L, 0L, 0L);
            gemm_bt<2><<<dim3(DD / 128, SS / 128, 1), 256, 0, stream>>>(
                h1, W2T, (float*)d_out + (long)b * SD, b2, xbf, SS, DD, GDIM, 0L, 0L, 0L);
        }
    }
}